// Round 7
// baseline (123.747 us; speedup 1.0000x reference)
//
#include <hip/hip_runtime.h>

#define BATCH 16
#define SEQ   1024
#define DM    512
#define NST   32

// E layout: [ssm][b][c][n][d]

// ---------------- setup: precompute dA and Cw=C*B*dt*w tables, layout [ssm][n][d]
__global__ __launch_bounds__(256) void ssm_setup(
    const float* __restrict__ Alog_hr, const float* __restrict__ B_hr,
    const float* __restrict__ C_hr,    const float* __restrict__ ldt_hr,
    const float* __restrict__ Alog_br, const float* __restrict__ B_br,
    const float* __restrict__ C_br,    const float* __restrict__ ldt_br,
    const float* __restrict__ w_hr,    const float* __restrict__ w_br,
    float* __restrict__ dA_tbl, float* __restrict__ Cw_tbl)
{
    int idx = blockIdx.x * blockDim.x + threadIdx.x;   // (ssm*NST + n)*DM + d
    int d   = idx & (DM - 1);
    int n   = (idx >> 9) & (NST - 1);
    int ssm = idx >> 14;

    const float* Alog = ssm ? Alog_br : Alog_hr;
    const float* Bm   = ssm ? B_br    : B_hr;
    const float* Cm   = ssm ? C_br    : C_hr;
    const float* ldt  = ssm ? ldt_br  : ldt_hr;
    const float* w    = ssm ? w_br    : w_hr;

    float dt = expf(ldt[d]);
    float a  = expf(Alog[d * NST + n]);
    dA_tbl[idx] = expf(dt * a);
    Cw_tbl[idx] = Cm[d * NST + n] * Bm[d * NST + n] * dt * w[d];
}

// ---------------- pass 1: local chunk scans, n-split: one ssm x 16 states per thread
__global__ __launch_bounds__(256) void ssm_pass1(
    const float* __restrict__ x,
    const float* __restrict__ dA_tbl,
    float* __restrict__ ws_state, int nc, int cl)
{
    int tid  = threadIdx.x;
    int dlo  = tid & 127;
    int nh   = tid >> 7;            // n-half
    int bid  = blockIdx.x;          // ((ssm*BATCH+b)*nc + c)*4 + dblk
    int dblk = bid & 3;
    int r    = bid >> 2;
    int c    = r % nc;  r /= nc;
    int b    = r & (BATCH - 1);
    int ssm  = r >> 4;
    int d    = dblk * 128 + dlo;
    int n0   = nh * 16;

    const float* tb = dA_tbl + ((size_t)ssm * NST + n0) * DM + d;
    float dA[16], g[16];
#pragma unroll
    for (int i = 0; i < 16; ++i) {
        dA[i] = tb[(size_t)i * DM];
        g[i]  = 0.f;
    }

    const float* xp = x + ((size_t)b * SEQ + (size_t)c * cl) * DM + d;
#pragma unroll 4
    for (int t = 0; t < cl; ++t) {
        float xv = *xp;  xp += DM;
#pragma unroll
        for (int i = 0; i < 16; ++i) g[i] = fmaf(dA[i], g[i], xv);
    }

    float* sp = ws_state + ((((size_t)ssm * BATCH + b) * nc + c) * NST + n0) * DM + d;
#pragma unroll
    for (int i = 0; i < 16; ++i) sp[(size_t)i * DM] = g[i];
}

// ---------------- pass 2: scan across chunks; rewrite ws with corrected chunk-INITIAL states
__global__ __launch_bounds__(256) void ssm_pass2(
    const float* __restrict__ Alog_hr, const float* __restrict__ ldt_hr,
    const float* __restrict__ Alog_br, const float* __restrict__ ldt_br,
    float* __restrict__ ws_state, int nc, int cl)
{
    int idx = blockIdx.x * blockDim.x + threadIdx.x;   // (((ssm*16+b)*NST+n)*DM + d)
    int d   = idx & (DM - 1);
    int n   = (idx >> 9) & (NST - 1);
    int b   = (idx >> 14) & 15;
    int ssm = idx >> 18;

    const float* Alog = ssm ? Alog_br : Alog_hr;
    const float* ldt  = ssm ? ldt_br  : ldt_hr;

    float dt = expf(ldt[d]);
    float A  = expf(Alog[d * NST + n]);
    float p  = expf((float)cl * dt * A);   // dA^cl

    float* sp = ws_state + ((((size_t)ssm * BATCH + b) * nc) * NST + n) * DM + d;
    size_t cstride = (size_t)NST * DM;

    float H = 0.f;
    for (int c = 0; c < nc; ++c) {
        float s = *sp;
        *sp = H;                 // init state for chunk c (H=0 at c=0)
        H = fmaf(p, H, s);       // end state of chunk c
        sp += cstride;
    }
}

// ---------------- pass 3: 8-way n-split (4 states/ssm/thread -> 24 live floats, no spill)
// lane = dlo(3b) | nq(3b); nq owns states [nq*4, nq*4+4); butterfly over lane bits 3,4,5.
// nq stores: 0->hr, 1->br, 2->combined, 3..7 masked.
__global__ __launch_bounds__(256) void ssm_pass3(
    const float* __restrict__ x,
    const float* __restrict__ dA_tbl, const float* __restrict__ Cw_tbl,
    const float* __restrict__ ws_state,
    float* __restrict__ out_hr, float* __restrict__ out_br, float* __restrict__ out_cb,
    int nc, int cl)
{
    int tid  = threadIdx.x;
    int lane = tid & 63;
    int wave = tid >> 6;
    int dlo  = lane & 7;
    int nq   = lane >> 3;
    int bid  = blockIdx.x;          // (b*nc + c)*16 + dblk
    int dblk = bid & 15;
    int r    = bid >> 4;
    int c    = r % nc;
    int b    = r / nc;
    int d    = dblk * 32 + wave * 8 + dlo;
    int n0   = nq * 4;

    float dAh[4], dAb[4], Cwh[4], Cwb[4];
#pragma unroll
    for (int i = 0; i < 4; ++i) {
        size_t ih = (size_t)(n0 + i) * DM + d;
        size_t ib = (size_t)(NST + n0 + i) * DM + d;
        dAh[i] = dA_tbl[ih];
        dAb[i] = dA_tbl[ib];
        Cwh[i] = Cw_tbl[ih];
        Cwb[i] = Cw_tbl[ib];
    }

    float gh[4], gb[4];
    if (c == 0) {
#pragma unroll
        for (int i = 0; i < 4; ++i) { gh[i] = 0.f; gb[i] = 0.f; }
    } else {
        const float* sph = ws_state + (((size_t)b * nc + c) * NST + n0) * DM + d;
        const float* spb = sph + (size_t)BATCH * nc * NST * DM;
#pragma unroll
        for (int i = 0; i < 4; ++i) {
            gh[i] = sph[(size_t)i * DM];
            gb[i] = spb[(size_t)i * DM];
        }
    }

    size_t off = ((size_t)b * SEQ + (size_t)c * cl) * DM + d;
    const float* xp = x + off;
    float* op = (nq == 0 ? out_hr : (nq == 1 ? out_br : out_cb)) + off;

#pragma unroll 4
    for (int t = 0; t < cl; ++t) {
        float xv = *xp;  xp += DM;

        float yh0 = 0.f, yh1 = 0.f, yb0 = 0.f, yb1 = 0.f;
#pragma unroll
        for (int i = 0; i < 4; i += 2) {
            gh[i]     = fmaf(dAh[i],     gh[i],     xv);
            gh[i + 1] = fmaf(dAh[i + 1], gh[i + 1], xv);
            gb[i]     = fmaf(dAb[i],     gb[i],     xv);
            gb[i + 1] = fmaf(dAb[i + 1], gb[i + 1], xv);
            yh0 = fmaf(Cwh[i],     gh[i],     yh0);
            yh1 = fmaf(Cwh[i + 1], gh[i + 1], yh1);
            yb0 = fmaf(Cwb[i],     gb[i],     yb0);
            yb1 = fmaf(Cwb[i + 1], gb[i + 1], yb1);
        }
        float yh = yh0 + yh1;
        float yb = yb0 + yb1;

        // butterfly over lane bits 3,4,5 (the nq bits)
        float th, tb_;
        th  = __shfl_xor(yh, 8, 64);
        tb_ = __shfl_xor(yb, 8, 64);
        yh += th;  yb += tb_;
        th  = __shfl_xor(yh, 16, 64);
        tb_ = __shfl_xor(yb, 16, 64);
        yh += th;  yb += tb_;
        th  = __shfl_xor(yh, 32, 64);
        tb_ = __shfl_xor(yb, 32, 64);
        yh += th;  yb += tb_;

        float val = (nq == 0) ? yh : ((nq == 1) ? yb : yh + yb);
        if (nq < 3) *op = val;
        op += DM;
    }
}

extern "C" void kernel_launch(void* const* d_in, const int* in_sizes, int n_in,
                              void* d_out, int out_size, void* d_ws, size_t ws_size,
                              hipStream_t stream)
{
    (void)in_sizes; (void)n_in; (void)out_size;

    const float* x       = (const float*)d_in[0];
    const float* Alog_hr = (const float*)d_in[1];
    const float* B_hr    = (const float*)d_in[2];
    const float* C_hr    = (const float*)d_in[3];
    const float* ldt_hr  = (const float*)d_in[4];
    const float* Alog_br = (const float*)d_in[5];
    const float* B_br    = (const float*)d_in[6];
    const float* C_br    = (const float*)d_in[7];
    const float* ldt_br  = (const float*)d_in[8];
    const float* w_hr    = (const float*)d_in[9];
    const float* w_br    = (const float*)d_in[10];

    float* out    = (float*)d_out;
    const size_t one = (size_t)BATCH * SEQ * DM;
    float* out_hr = out;
    float* out_br = out + one;
    float* out_cb = out + 2 * one;

    // ws layout: [dA_tbl 2*NST*DM][Cw_tbl 2*NST*DM][chunk states 2*BATCH*nc*NST*DM]
    float* dA_tbl = (float*)d_ws;
    float* Cw_tbl = dA_tbl + (size_t)2 * NST * DM;
    float* ws_st  = Cw_tbl + (size_t)2 * NST * DM;

    const size_t tbl_bytes = (size_t)4 * NST * DM * sizeof(float);
    int nc = 8;
    while (nc > 1 &&
           ws_size < tbl_bytes + (size_t)2 * BATCH * nc * NST * DM * sizeof(float))
        nc >>= 1;
    int cl = SEQ / nc;

    int total0 = 2 * NST * DM;
    ssm_setup<<<total0 / 256, 256, 0, stream>>>(Alog_hr, B_hr, C_hr, ldt_hr,
                                                Alog_br, B_br, C_br, ldt_br,
                                                w_hr, w_br, dA_tbl, Cw_tbl);

    if (nc > 1) {
        int nblk1 = 2 * BATCH * nc * 4;          // (ssm,b,c) x 4 d-blocks of 128 (x2 nh)
        ssm_pass1<<<nblk1, 256, 0, stream>>>(x, dA_tbl, ws_st, nc, cl);
        int total2 = 2 * BATCH * NST * DM;
        ssm_pass2<<<total2 / 256, 256, 0, stream>>>(Alog_hr, ldt_hr, Alog_br, ldt_br,
                                                    ws_st, nc, cl);
    }

    int nblk3 = BATCH * nc * 16;                 // (b,c) x 16 d-blocks of 32 (x8 nq)
    ssm_pass3<<<nblk3, 256, 0, stream>>>(x, dA_tbl, Cw_tbl, ws_st,
                                         out_hr, out_br, out_cb, nc, cl);
}

// Round 8
// 100.422 us; speedup vs baseline: 1.2323x; 1.2323x over previous
//
#include <hip/hip_runtime.h>

#define BATCH 16
#define SEQ   1024
#define DM    512
#define NST   32

// E layout: [ssm][b][c][n][d]

// Pin a float into a VGPR: opaque no-op asm -> compiler cannot rematerialize
// (re-load from memory) past this point; forces true register residency.
#define PIN(v) asm volatile("" : "+v"(v))

// ---------------- setup: precompute dA and Cw=C*B*dt*w tables, layout [ssm][n][d]
__global__ __launch_bounds__(256) void ssm_setup(
    const float* __restrict__ Alog_hr, const float* __restrict__ B_hr,
    const float* __restrict__ C_hr,    const float* __restrict__ ldt_hr,
    const float* __restrict__ Alog_br, const float* __restrict__ B_br,
    const float* __restrict__ C_br,    const float* __restrict__ ldt_br,
    const float* __restrict__ w_hr,    const float* __restrict__ w_br,
    float* __restrict__ dA_tbl, float* __restrict__ Cw_tbl)
{
    int idx = blockIdx.x * blockDim.x + threadIdx.x;   // (ssm*NST + n)*DM + d
    int d   = idx & (DM - 1);
    int n   = (idx >> 9) & (NST - 1);
    int ssm = idx >> 14;

    const float* Alog = ssm ? Alog_br : Alog_hr;
    const float* Bm   = ssm ? B_br    : B_hr;
    const float* Cm   = ssm ? C_br    : C_hr;
    const float* ldt  = ssm ? ldt_br  : ldt_hr;
    const float* w    = ssm ? w_br    : w_hr;

    float dt = expf(ldt[d]);
    float a  = expf(Alog[d * NST + n]);
    dA_tbl[idx] = expf(dt * a);
    Cw_tbl[idx] = Cm[d * NST + n] * Bm[d * NST + n] * dt * w[d];
}

// ---------------- pass 1: local chunk scans, n-split: one ssm x 16 states per thread
__global__ __launch_bounds__(256, 2) void ssm_pass1(
    const float* __restrict__ x,
    const float* __restrict__ dA_tbl,
    float* __restrict__ ws_state, int nc, int cl)
{
    int tid  = threadIdx.x;
    int dlo  = tid & 127;
    int nh   = tid >> 7;            // n-half
    int bid  = blockIdx.x;          // ((ssm*BATCH+b)*nc + c)*4 + dblk
    int dblk = bid & 3;
    int r    = bid >> 2;
    int c    = r % nc;  r /= nc;
    int b    = r & (BATCH - 1);
    int ssm  = r >> 4;
    int d    = dblk * 128 + dlo;
    int n0   = nh * 16;

    const float* tb = dA_tbl + ((size_t)ssm * NST + n0) * DM + d;
    float dA[16], g[16];
#pragma unroll
    for (int i = 0; i < 16; ++i) {
        dA[i] = tb[(size_t)i * DM];
        g[i]  = 0.f;
    }
#pragma unroll
    for (int i = 0; i < 16; ++i) PIN(dA[i]);

    const float* xp = x + ((size_t)b * SEQ + (size_t)c * cl) * DM + d;
#pragma unroll 4
    for (int t = 0; t < cl; ++t) {
        float xv = *xp;  xp += DM;
#pragma unroll
        for (int i = 0; i < 16; ++i) g[i] = fmaf(dA[i], g[i], xv);
    }

    float* sp = ws_state + ((((size_t)ssm * BATCH + b) * nc + c) * NST + n0) * DM + d;
#pragma unroll
    for (int i = 0; i < 16; ++i) sp[(size_t)i * DM] = g[i];
}

// ---------------- pass 2: scan across chunks; rewrite ws with corrected chunk-INITIAL states
__global__ __launch_bounds__(256) void ssm_pass2(
    const float* __restrict__ Alog_hr, const float* __restrict__ ldt_hr,
    const float* __restrict__ Alog_br, const float* __restrict__ ldt_br,
    float* __restrict__ ws_state, int nc, int cl)
{
    int idx = blockIdx.x * blockDim.x + threadIdx.x;   // (((ssm*16+b)*NST+n)*DM + d)
    int d   = idx & (DM - 1);
    int n   = (idx >> 9) & (NST - 1);
    int b   = (idx >> 14) & 15;
    int ssm = idx >> 18;

    const float* Alog = ssm ? Alog_br : Alog_hr;
    const float* ldt  = ssm ? ldt_br  : ldt_hr;

    float dt = expf(ldt[d]);
    float A  = expf(Alog[d * NST + n]);
    float p  = expf((float)cl * dt * A);   // dA^cl

    float* sp = ws_state + ((((size_t)ssm * BATCH + b) * nc) * NST + n) * DM + d;
    size_t cstride = (size_t)NST * DM;

    float H = 0.f;
    for (int c = 0; c < nc; ++c) {
        float s = *sp;
        *sp = H;                 // init state for chunk c (H=0 at c=0)
        H = fmaf(p, H, s);       // end state of chunk c
        sp += cstride;
    }
}

// ---------------- pass 3: 4-way n-split (8 states/ssm/thread, coeffs PINNED in VGPRs)
// lane = dlo(4b) | nq(2b); nq owns states [nq*8, nq*8+8); butterfly over lane bits 4,5.
// nq stores: 0->hr, 1->br, 2->combined, 3 masked (duplicate).
__global__ __launch_bounds__(256, 2) void ssm_pass3(
    const float* __restrict__ x,
    const float* __restrict__ dA_tbl, const float* __restrict__ Cw_tbl,
    const float* __restrict__ ws_state,
    float* __restrict__ out_hr, float* __restrict__ out_br, float* __restrict__ out_cb,
    int nc, int cl)
{
    int tid  = threadIdx.x;
    int lane = tid & 63;
    int wave = tid >> 6;
    int nq   = lane >> 4;
    int dlo  = lane & 15;
    int bid  = blockIdx.x;          // (b*nc + c)*8 + dblk
    int dblk = bid & 7;
    int r    = bid >> 3;
    int c    = r % nc;
    int b    = r / nc;
    int d    = (dblk << 6) + (wave << 4) + dlo;
    int n0   = nq * 8;

    float dAh[8], dAb[8], Cwh[8], Cwb[8];
#pragma unroll
    for (int i = 0; i < 8; ++i) {
        size_t ih = (size_t)(n0 + i) * DM + d;
        size_t ib = (size_t)(NST + n0 + i) * DM + d;
        dAh[i] = dA_tbl[ih];
        dAb[i] = dA_tbl[ib];
        Cwh[i] = Cw_tbl[ih];
        Cwb[i] = Cw_tbl[ib];
    }
#pragma unroll
    for (int i = 0; i < 8; ++i) {
        PIN(dAh[i]); PIN(dAb[i]); PIN(Cwh[i]); PIN(Cwb[i]);
    }

    float gh[8], gb[8];
    if (c == 0) {
#pragma unroll
        for (int i = 0; i < 8; ++i) { gh[i] = 0.f; gb[i] = 0.f; }
    } else {
        const float* sph = ws_state + (((size_t)b * nc + c) * NST + n0) * DM + d;
        const float* spb = sph + (size_t)BATCH * nc * NST * DM;
#pragma unroll
        for (int i = 0; i < 8; ++i) {
            gh[i] = sph[(size_t)i * DM];
            gb[i] = spb[(size_t)i * DM];
        }
    }

    size_t off = ((size_t)b * SEQ + (size_t)c * cl) * DM + d;
    const float* xp = x + off;
    float* op = (nq == 0 ? out_hr : (nq == 1 ? out_br : out_cb)) + off;

#pragma unroll 2
    for (int t = 0; t < cl; ++t) {
        float xv = *xp;  xp += DM;

        float yh0 = 0.f, yh1 = 0.f, yb0 = 0.f, yb1 = 0.f;
#pragma unroll
        for (int i = 0; i < 8; i += 2) {
            gh[i]     = fmaf(dAh[i],     gh[i],     xv);
            gh[i + 1] = fmaf(dAh[i + 1], gh[i + 1], xv);
            gb[i]     = fmaf(dAb[i],     gb[i],     xv);
            gb[i + 1] = fmaf(dAb[i + 1], gb[i + 1], xv);
            yh0 = fmaf(Cwh[i],     gh[i],     yh0);
            yh1 = fmaf(Cwh[i + 1], gh[i + 1], yh1);
            yb0 = fmaf(Cwb[i],     gb[i],     yb0);
            yb1 = fmaf(Cwb[i + 1], gb[i + 1], yb1);
        }
        float yh = yh0 + yh1;
        float yb = yb0 + yb1;

        // reduce over nq (lane bits 4,5)
        float th  = __shfl_xor(yh, 16, 64);
        float tb_ = __shfl_xor(yb, 16, 64);
        yh += th;  yb += tb_;
        th  = __shfl_xor(yh, 32, 64);
        tb_ = __shfl_xor(yb, 32, 64);
        yh += th;  yb += tb_;

        float val = (nq == 0) ? yh : ((nq == 1) ? yb : yh + yb);
        if (nq < 3) *op = val;          // nq=3 would duplicate nq=2's combined write
        op += DM;
    }
}

extern "C" void kernel_launch(void* const* d_in, const int* in_sizes, int n_in,
                              void* d_out, int out_size, void* d_ws, size_t ws_size,
                              hipStream_t stream)
{
    (void)in_sizes; (void)n_in; (void)out_size;

    const float* x       = (const float*)d_in[0];
    const float* Alog_hr = (const float*)d_in[1];
    const float* B_hr    = (const float*)d_in[2];
    const float* C_hr    = (const float*)d_in[3];
    const float* ldt_hr  = (const float*)d_in[4];
    const float* Alog_br = (const float*)d_in[5];
    const float* B_br    = (const float*)d_in[6];
    const float* C_br    = (const float*)d_in[7];
    const float* ldt_br  = (const float*)d_in[8];
    const float* w_hr    = (const float*)d_in[9];
    const float* w_br    = (const float*)d_in[10];

    float* out    = (float*)d_out;
    const size_t one = (size_t)BATCH * SEQ * DM;
    float* out_hr = out;
    float* out_br = out + one;
    float* out_cb = out + 2 * one;

    // ws layout: [dA_tbl 2*NST*DM][Cw_tbl 2*NST*DM][chunk states 2*BATCH*nc*NST*DM]
    float* dA_tbl = (float*)d_ws;
    float* Cw_tbl = dA_tbl + (size_t)2 * NST * DM;
    float* ws_st  = Cw_tbl + (size_t)2 * NST * DM;

    const size_t tbl_bytes = (size_t)4 * NST * DM * sizeof(float);
    int nc = 8;
    while (nc > 1 &&
           ws_size < tbl_bytes + (size_t)2 * BATCH * nc * NST * DM * sizeof(float))
        nc >>= 1;
    int cl = SEQ / nc;

    int total0 = 2 * NST * DM;
    ssm_setup<<<total0 / 256, 256, 0, stream>>>(Alog_hr, B_hr, C_hr, ldt_hr,
                                                Alog_br, B_br, C_br, ldt_br,
                                                w_hr, w_br, dA_tbl, Cw_tbl);

    if (nc > 1) {
        int nblk1 = 2 * BATCH * nc * 4;          // (ssm,b,c) x 4 d-blocks of 128 (x2 nh)
        ssm_pass1<<<nblk1, 256, 0, stream>>>(x, dA_tbl, ws_st, nc, cl);
        int total2 = 2 * BATCH * NST * DM;
        ssm_pass2<<<total2 / 256, 256, 0, stream>>>(Alog_hr, ldt_hr, Alog_br, ldt_br,
                                                    ws_st, nc, cl);
    }

    int nblk3 = BATCH * nc * 8;                  // (b,c) x 8 d-blocks of 64 (x4 nq)
    ssm_pass3<<<nblk3, 256, 0, stream>>>(x, dA_tbl, Cw_tbl, ws_st,
                                         out_hr, out_br, out_cb, nc, cl);
}

// Round 9
// 99.758 us; speedup vs baseline: 1.2405x; 1.0067x over previous
//
#include <hip/hip_runtime.h>

#define BATCH 16
#define SEQ   1024
#define DM    512
#define NST   32

#define PIN(v) asm volatile("" : "+v"(v))

// ---------------- setup: precompute dA and Cw=C*B*dt*w tables, layout [ssm][n][d]
__global__ __launch_bounds__(256) void ssm_setup(
    const float* __restrict__ Alog_hr, const float* __restrict__ B_hr,
    const float* __restrict__ C_hr,    const float* __restrict__ ldt_hr,
    const float* __restrict__ Alog_br, const float* __restrict__ B_br,
    const float* __restrict__ C_br,    const float* __restrict__ ldt_br,
    const float* __restrict__ w_hr,    const float* __restrict__ w_br,
    float* __restrict__ dA_tbl, float* __restrict__ Cw_tbl)
{
    int idx = blockIdx.x * blockDim.x + threadIdx.x;   // (ssm*NST + n)*DM + d
    int d   = idx & (DM - 1);
    int n   = (idx >> 9) & (NST - 1);
    int ssm = idx >> 14;

    const float* Alog = ssm ? Alog_br : Alog_hr;
    const float* Bm   = ssm ? B_br    : B_hr;
    const float* Cm   = ssm ? C_br    : C_hr;
    const float* ldt  = ssm ? ldt_br  : ldt_hr;
    const float* w    = ssm ? w_br    : w_hr;

    float dt = expf(ldt[d]);
    float a  = expf(Alog[d * NST + n]);
    dA_tbl[idx] = expf(dt * a);
    Cw_tbl[idx] = Cm[d * NST + n] * Bm[d * NST + n] * dt * w[d];
}

// ---------------- pass 1: local chunk scans, n-split: one ssm x 16 states per thread
__global__ __launch_bounds__(256, 2) void ssm_pass1(
    const float* __restrict__ x,
    const float* __restrict__ dA_tbl,
    float* __restrict__ ws_state, int nc, int cl)
{
    int tid  = threadIdx.x;
    int dlo  = tid & 127;
    int nh   = tid >> 7;            // n-half
    int bid  = blockIdx.x;          // ((ssm*BATCH+b)*nc + c)*4 + dblk
    int dblk = bid & 3;
    int r    = bid >> 2;
    int c    = r % nc;  r /= nc;
    int b    = r & (BATCH - 1);
    int ssm  = r >> 4;
    int d    = dblk * 128 + dlo;
    int n0   = nh * 16;

    const float* tb = dA_tbl + ((size_t)ssm * NST + n0) * DM + d;
    float dA[16], g[16];
#pragma unroll
    for (int i = 0; i < 16; ++i) {
        dA[i] = tb[(size_t)i * DM];
        g[i]  = 0.f;
    }
#pragma unroll
    for (int i = 0; i < 16; ++i) PIN(dA[i]);

    const float* xp = x + ((size_t)b * SEQ + (size_t)c * cl) * DM + d;
#pragma unroll 4
    for (int t = 0; t < cl; ++t) {
        float xv = *xp;  xp += DM;
#pragma unroll
        for (int i = 0; i < 16; ++i) g[i] = fmaf(dA[i], g[i], xv);
    }

    float* sp = ws_state + ((((size_t)ssm * BATCH + b) * nc + c) * NST + n0) * DM + d;
#pragma unroll
    for (int i = 0; i < 16; ++i) sp[(size_t)i * DM] = g[i];
}

// ---------------- pass 2: scan across chunks; rewrite ws with corrected chunk-INITIAL states
__global__ __launch_bounds__(256) void ssm_pass2(
    const float* __restrict__ Alog_hr, const float* __restrict__ ldt_hr,
    const float* __restrict__ Alog_br, const float* __restrict__ ldt_br,
    float* __restrict__ ws_state, int nc, int cl)
{
    int idx = blockIdx.x * blockDim.x + threadIdx.x;   // (((ssm*16+b)*NST+n)*DM + d)
    int d   = idx & (DM - 1);
    int n   = (idx >> 9) & (NST - 1);
    int b   = (idx >> 14) & 15;
    int ssm = idx >> 18;

    const float* Alog = ssm ? Alog_br : Alog_hr;
    const float* ldt  = ssm ? ldt_br  : ldt_hr;

    float dt = expf(ldt[d]);
    float A  = expf(Alog[d * NST + n]);
    float p  = expf((float)cl * dt * A);   // dA^cl

    float* sp = ws_state + ((((size_t)ssm * BATCH + b) * nc) * NST + n) * DM + d;
    size_t cstride = (size_t)NST * DM;

    float H = 0.f;
    for (int c = 0; c < nc; ++c) {
        float s = *sp;
        *sp = H;                 // init state for chunk c (H=0 at c=0)
        H = fmaf(p, H, s);       // end state of chunk c
        sp += cstride;
    }
}

// ---------------- pass 3: ssm-split across wave halves; full 32 states per thread; no n-reduce.
// lanes 0-31: hr for d=base..base+31; lanes 32-63: br for the same d.
// One shfl_xor(32) per t swaps y across halves; hr-lane stores hr & combined, br-lane stores br.
// Live set ~110 floats == the budget the allocator demonstrably grants (R2: 108).
__global__ __launch_bounds__(128, 2) void ssm_pass3(
    const float* __restrict__ x,
    const float* __restrict__ dA_tbl, const float* __restrict__ Cw_tbl,
    const float* __restrict__ ws_state,
    float* __restrict__ out_hr, float* __restrict__ out_br, float* __restrict__ out_cb,
    int nc, int cl)
{
    int tid  = threadIdx.x;          // 128 threads = 2 waves
    int lane = tid & 63;
    int wid  = tid >> 6;
    int ssm  = lane >> 5;            // 0 -> hr, 1 -> br
    int dlo  = lane & 31;
    int bid  = blockIdx.x;           // (b*nc + c)*8 + dblk
    int dblk = bid & 7;
    int r    = bid >> 3;
    int c    = r % nc;
    int b    = r / nc;
    int d    = dblk * 64 + wid * 32 + dlo;

    const float* dat = dA_tbl + (size_t)ssm * NST * DM + d;
    const float* cwt = Cw_tbl + (size_t)ssm * NST * DM + d;
    float dA[NST], Cw[NST];
#pragma unroll
    for (int n = 0; n < NST; ++n) {
        dA[n] = dat[(size_t)n * DM];
        Cw[n] = cwt[(size_t)n * DM];
    }
#pragma unroll
    for (int n = 0; n < NST; ++n) { PIN(dA[n]); PIN(Cw[n]); }

    float g[NST];
    if (c == 0) {
#pragma unroll
        for (int n = 0; n < NST; ++n) g[n] = 0.f;
    } else {
        const float* sp = ws_state + ((((size_t)ssm * BATCH + b) * nc + c) * NST) * DM + d;
#pragma unroll
        for (int n = 0; n < NST; ++n) g[n] = sp[(size_t)n * DM];
    }

    size_t off = ((size_t)b * SEQ + (size_t)c * cl) * DM + d;
    const float* xp = x + off;
    float* oh = out_hr + off;
    float* ob = out_br + off;
    float* oc = out_cb + off;

#pragma unroll 2
    for (int t = 0; t < cl; ++t) {
        float xv = *xp;  xp += DM;

        float y0 = 0.f, y1 = 0.f, y2 = 0.f, y3 = 0.f;
#pragma unroll
        for (int n = 0; n < NST; n += 4) {
            g[n]     = fmaf(dA[n],     g[n],     xv);
            g[n + 1] = fmaf(dA[n + 1], g[n + 1], xv);
            g[n + 2] = fmaf(dA[n + 2], g[n + 2], xv);
            g[n + 3] = fmaf(dA[n + 3], g[n + 3], xv);
            y0 = fmaf(Cw[n],     g[n],     y0);
            y1 = fmaf(Cw[n + 1], g[n + 1], y1);
            y2 = fmaf(Cw[n + 2], g[n + 2], y2);
            y3 = fmaf(Cw[n + 3], g[n + 3], y3);
        }
        float y  = (y0 + y1) + (y2 + y3);
        float yo = __shfl_xor(y, 32, 64);    // the other ssm's y for this d

        if (ssm == 0) {
            *oh = y;
            *oc = y + yo;
        } else {
            *ob = y;
        }
        oh += DM;  ob += DM;  oc += DM;
    }
}

extern "C" void kernel_launch(void* const* d_in, const int* in_sizes, int n_in,
                              void* d_out, int out_size, void* d_ws, size_t ws_size,
                              hipStream_t stream)
{
    (void)in_sizes; (void)n_in; (void)out_size;

    const float* x       = (const float*)d_in[0];
    const float* Alog_hr = (const float*)d_in[1];
    const float* B_hr    = (const float*)d_in[2];
    const float* C_hr    = (const float*)d_in[3];
    const float* ldt_hr  = (const float*)d_in[4];
    const float* Alog_br = (const float*)d_in[5];
    const float* B_br    = (const float*)d_in[6];
    const float* C_br    = (const float*)d_in[7];
    const float* ldt_br  = (const float*)d_in[8];
    const float* w_hr    = (const float*)d_in[9];
    const float* w_br    = (const float*)d_in[10];

    float* out    = (float*)d_out;
    const size_t one = (size_t)BATCH * SEQ * DM;
    float* out_hr = out;
    float* out_br = out + one;
    float* out_cb = out + 2 * one;

    // ws layout: [dA_tbl 2*NST*DM][Cw_tbl 2*NST*DM][chunk states 2*BATCH*nc*NST*DM]
    float* dA_tbl = (float*)d_ws;
    float* Cw_tbl = dA_tbl + (size_t)2 * NST * DM;
    float* ws_st  = Cw_tbl + (size_t)2 * NST * DM;

    const size_t tbl_bytes = (size_t)4 * NST * DM * sizeof(float);
    int nc = 8;
    while (nc > 1 &&
           ws_size < tbl_bytes + (size_t)2 * BATCH * nc * NST * DM * sizeof(float))
        nc >>= 1;
    int cl = SEQ / nc;

    int total0 = 2 * NST * DM;
    ssm_setup<<<total0 / 256, 256, 0, stream>>>(Alog_hr, B_hr, C_hr, ldt_hr,
                                                Alog_br, B_br, C_br, ldt_br,
                                                w_hr, w_br, dA_tbl, Cw_tbl);

    if (nc > 1) {
        int nblk1 = 2 * BATCH * nc * 4;          // (ssm,b,c) x 4 d-blocks of 128 (x2 nh)
        ssm_pass1<<<nblk1, 256, 0, stream>>>(x, dA_tbl, ws_st, nc, cl);
        int total2 = 2 * BATCH * NST * DM;
        ssm_pass2<<<total2 / 256, 256, 0, stream>>>(Alog_hr, ldt_hr, Alog_br, ldt_br,
                                                    ws_st, nc, cl);
    }

    int nblk3 = BATCH * nc * 8;                  // (b,c) x 8 d-blocks of 64 (x2 waves, ssm-split lanes)
    ssm_pass3<<<nblk3, 128, 0, stream>>>(x, dA_tbl, Cw_tbl, ws_st,
                                         out_hr, out_br, out_cb, nc, cl);
}

// Round 10
// 76.700 us; speedup vs baseline: 1.6134x; 1.3006x over previous
//
#include <hip/hip_runtime.h>

#define BATCH 16
#define SEQ   1024
#define DM    512
#define NST   32
#define PF    8     // x-prefetch depth (register ring, statically indexed)

#define PIN(v) asm volatile("" : "+v"(v))

// ---------------- setup: precompute dA and Cw=C*B*dt*w tables, layout [ssm][n][d]
__global__ __launch_bounds__(256) void ssm_setup(
    const float* __restrict__ Alog_hr, const float* __restrict__ B_hr,
    const float* __restrict__ C_hr,    const float* __restrict__ ldt_hr,
    const float* __restrict__ Alog_br, const float* __restrict__ B_br,
    const float* __restrict__ C_br,    const float* __restrict__ ldt_br,
    const float* __restrict__ w_hr,    const float* __restrict__ w_br,
    float* __restrict__ dA_tbl, float* __restrict__ Cw_tbl)
{
    int idx = blockIdx.x * blockDim.x + threadIdx.x;   // (ssm*NST + n)*DM + d
    int d   = idx & (DM - 1);
    int n   = (idx >> 9) & (NST - 1);
    int ssm = idx >> 14;

    const float* Alog = ssm ? Alog_br : Alog_hr;
    const float* Bm   = ssm ? B_br    : B_hr;
    const float* Cm   = ssm ? C_br    : C_hr;
    const float* ldt  = ssm ? ldt_br  : ldt_hr;
    const float* w    = ssm ? w_br    : w_hr;

    float dt = expf(ldt[d]);
    float a  = expf(Alog[d * NST + n]);
    dA_tbl[idx] = expf(dt * a);
    Cw_tbl[idx] = Cm[d * NST + n] * Bm[d * NST + n] * dt * w[d];
}

// ---------------- pass 1: local chunk scans, n-split, 8-deep x prefetch
__global__ __launch_bounds__(256) void ssm_pass1(
    const float* __restrict__ x,
    const float* __restrict__ dA_tbl,
    float* __restrict__ ws_state, int nc, int cl)
{
    int tid  = threadIdx.x;
    int dlo  = tid & 127;
    int nh   = tid >> 7;            // n-half
    int bid  = blockIdx.x;          // ((ssm*BATCH+b)*nc + c)*4 + dblk
    int dblk = bid & 3;
    int r    = bid >> 2;
    int c    = r % nc;  r /= nc;
    int b    = r & (BATCH - 1);
    int ssm  = r >> 4;
    int d    = dblk * 128 + dlo;
    int n0   = nh * 16;

    const float* tb = dA_tbl + ((size_t)ssm * NST + n0) * DM + d;
    float dA[16], g[16];
#pragma unroll
    for (int i = 0; i < 16; ++i) {
        dA[i] = tb[(size_t)i * DM];
        g[i]  = 0.f;
    }
#pragma unroll
    for (int i = 0; i < 16; ++i) PIN(dA[i]);

    const float* xp = x + ((size_t)b * SEQ + (size_t)c * cl) * DM + d;

    float xf[PF];
#pragma unroll
    for (int k = 0; k < PF; ++k) xf[k] = xp[(size_t)k * DM];
    const float* xq = xp + (size_t)PF * DM;

    int ntb = cl / PF;
    for (int t8 = 0; t8 < ntb - 1; ++t8) {
#pragma unroll
        for (int j = 0; j < PF; ++j) {
            float xv = xf[j];
            xf[j] = xq[(size_t)j * DM];          // prefetch t+PF
#pragma unroll
            for (int i = 0; i < 16; ++i) g[i] = fmaf(dA[i], g[i], xv);
        }
        xq += (size_t)PF * DM;
    }
#pragma unroll
    for (int j = 0; j < PF; ++j) {               // tail: no prefetch
        float xv = xf[j];
#pragma unroll
        for (int i = 0; i < 16; ++i) g[i] = fmaf(dA[i], g[i], xv);
    }

    float* sp = ws_state + ((((size_t)ssm * BATCH + b) * nc + c) * NST + n0) * DM + d;
#pragma unroll
    for (int i = 0; i < 16; ++i) sp[(size_t)i * DM] = g[i];
}

// ---------------- pass 2: scan across chunks; rewrite ws with corrected chunk-INITIAL states
__global__ __launch_bounds__(256) void ssm_pass2(
    const float* __restrict__ Alog_hr, const float* __restrict__ ldt_hr,
    const float* __restrict__ Alog_br, const float* __restrict__ ldt_br,
    float* __restrict__ ws_state, int nc, int cl)
{
    int idx = blockIdx.x * blockDim.x + threadIdx.x;   // (((ssm*16+b)*NST+n)*DM + d)
    int d   = idx & (DM - 1);
    int n   = (idx >> 9) & (NST - 1);
    int b   = (idx >> 14) & 15;
    int ssm = idx >> 18;

    const float* Alog = ssm ? Alog_br : Alog_hr;
    const float* ldt  = ssm ? ldt_br  : ldt_hr;

    float dt = expf(ldt[d]);
    float A  = expf(Alog[d * NST + n]);
    float p  = expf((float)cl * dt * A);   // dA^cl

    float* sp = ws_state + ((((size_t)ssm * BATCH + b) * nc) * NST + n) * DM + d;
    size_t cstride = (size_t)NST * DM;

    float H = 0.f;
    for (int c = 0; c < nc; ++c) {
        float s = *sp;
        *sp = H;                 // init state for chunk c (H=0 at c=0)
        H = fmaf(p, H, s);       // end state of chunk c
        sp += cstride;
    }
}

// ---------------- pass 3: ssm-split wave halves (R9 structure) + 8-deep x prefetch
// lanes 0-31: hr, lanes 32-63: br for the same 32 d's; one shfl_xor(32)/t for combined.
__global__ __launch_bounds__(128, 2) void ssm_pass3(
    const float* __restrict__ x,
    const float* __restrict__ dA_tbl, const float* __restrict__ Cw_tbl,
    const float* __restrict__ ws_state,
    float* __restrict__ out_hr, float* __restrict__ out_br, float* __restrict__ out_cb,
    int nc, int cl)
{
    int tid  = threadIdx.x;          // 128 threads = 2 waves
    int lane = tid & 63;
    int wid  = tid >> 6;
    int ssm  = lane >> 5;            // 0 -> hr, 1 -> br
    int dlo  = lane & 31;
    int bid  = blockIdx.x;           // (b*nc + c)*8 + dblk
    int dblk = bid & 7;
    int r    = bid >> 3;
    int c    = r % nc;
    int b    = r / nc;
    int d    = dblk * 64 + wid * 32 + dlo;

    const float* dat = dA_tbl + (size_t)ssm * NST * DM + d;
    const float* cwt = Cw_tbl + (size_t)ssm * NST * DM + d;
    float dA[NST], Cw[NST];
#pragma unroll
    for (int n = 0; n < NST; ++n) {
        dA[n] = dat[(size_t)n * DM];
        Cw[n] = cwt[(size_t)n * DM];
    }
#pragma unroll
    for (int n = 0; n < NST; ++n) { PIN(dA[n]); PIN(Cw[n]); }

    float g[NST];
    if (c == 0) {
#pragma unroll
        for (int n = 0; n < NST; ++n) g[n] = 0.f;
    } else {
        const float* sp = ws_state + ((((size_t)ssm * BATCH + b) * nc + c) * NST) * DM + d;
#pragma unroll
        for (int n = 0; n < NST; ++n) g[n] = sp[(size_t)n * DM];
    }

    size_t off = ((size_t)b * SEQ + (size_t)c * cl) * DM + d;
    const float* xp = x + off;
    float* oh = out_hr + off;
    float* ob = out_br + off;
    float* oc = out_cb + off;

    float xf[PF];
#pragma unroll
    for (int k = 0; k < PF; ++k) xf[k] = xp[(size_t)k * DM];
    const float* xq = xp + (size_t)PF * DM;

#define BODY(xv)                                                        \
    {                                                                   \
        float y0 = 0.f, y1 = 0.f, y2 = 0.f, y3 = 0.f;                   \
        _Pragma("unroll")                                               \
        for (int n = 0; n < NST; n += 4) {                              \
            g[n]     = fmaf(dA[n],     g[n],     xv);                   \
            g[n + 1] = fmaf(dA[n + 1], g[n + 1], xv);                   \
            g[n + 2] = fmaf(dA[n + 2], g[n + 2], xv);                   \
            g[n + 3] = fmaf(dA[n + 3], g[n + 3], xv);                   \
            y0 = fmaf(Cw[n],     g[n],     y0);                         \
            y1 = fmaf(Cw[n + 1], g[n + 1], y1);                         \
            y2 = fmaf(Cw[n + 2], g[n + 2], y2);                         \
            y3 = fmaf(Cw[n + 3], g[n + 3], y3);                         \
        }                                                               \
        float y  = (y0 + y1) + (y2 + y3);                               \
        float yo = __shfl_xor(y, 32, 64);                               \
        if (ssm == 0) { *oh = y; *oc = y + yo; }                        \
        else          { *ob = y; }                                      \
        oh += DM;  ob += DM;  oc += DM;                                 \
    }

    int ntb = cl / PF;
    for (int t8 = 0; t8 < ntb - 1; ++t8) {
#pragma unroll
        for (int j = 0; j < PF; ++j) {
            float xv = xf[j];
            xf[j] = xq[(size_t)j * DM];          // prefetch t+PF
            BODY(xv);
        }
        xq += (size_t)PF * DM;
    }
#pragma unroll
    for (int j = 0; j < PF; ++j) {               // tail: no prefetch
        float xv = xf[j];
        BODY(xv);
    }
#undef BODY
}

extern "C" void kernel_launch(void* const* d_in, const int* in_sizes, int n_in,
                              void* d_out, int out_size, void* d_ws, size_t ws_size,
                              hipStream_t stream)
{
    (void)in_sizes; (void)n_in; (void)out_size;

    const float* x       = (const float*)d_in[0];
    const float* Alog_hr = (const float*)d_in[1];
    const float* B_hr    = (const float*)d_in[2];
    const float* C_hr    = (const float*)d_in[3];
    const float* ldt_hr  = (const float*)d_in[4];
    const float* Alog_br = (const float*)d_in[5];
    const float* B_br    = (const float*)d_in[6];
    const float* C_br    = (const float*)d_in[7];
    const float* ldt_br  = (const float*)d_in[8];
    const float* w_hr    = (const float*)d_in[9];
    const float* w_br    = (const float*)d_in[10];

    float* out    = (float*)d_out;
    const size_t one = (size_t)BATCH * SEQ * DM;
    float* out_hr = out;
    float* out_br = out + one;
    float* out_cb = out + 2 * one;

    // ws layout: [dA_tbl 2*NST*DM][Cw_tbl 2*NST*DM][chunk states 2*BATCH*nc*NST*DM]
    float* dA_tbl = (float*)d_ws;
    float* Cw_tbl = dA_tbl + (size_t)2 * NST * DM;
    float* ws_st  = Cw_tbl + (size_t)2 * NST * DM;

    const size_t tbl_bytes = (size_t)4 * NST * DM * sizeof(float);
    int nc = 8;
    while (nc > 1 &&
           ws_size < tbl_bytes + (size_t)2 * BATCH * nc * NST * DM * sizeof(float))
        nc >>= 1;
    int cl = SEQ / nc;

    int total0 = 2 * NST * DM;
    ssm_setup<<<total0 / 256, 256, 0, stream>>>(Alog_hr, B_hr, C_hr, ldt_hr,
                                                Alog_br, B_br, C_br, ldt_br,
                                                w_hr, w_br, dA_tbl, Cw_tbl);

    if (nc > 1) {
        int nblk1 = 2 * BATCH * nc * 4;          // (ssm,b,c) x 4 d-blocks of 128 (x2 nh)
        ssm_pass1<<<nblk1, 256, 0, stream>>>(x, dA_tbl, ws_st, nc, cl);
        int total2 = 2 * BATCH * NST * DM;
        ssm_pass2<<<total2 / 256, 256, 0, stream>>>(Alog_hr, ldt_hr, Alog_br, ldt_br,
                                                    ws_st, nc, cl);
    }

    int nblk3 = BATCH * nc * 8;                  // (b,c) x 8 d-blocks of 64 (2 waves, ssm-split lanes)
    ssm_pass3<<<nblk3, 128, 0, stream>>>(x, dA_tbl, Cw_tbl, ws_st,
                                         out_hr, out_br, out_cb, nc, cl);
}